// Round 9
// baseline (125.105 us; speedup 1.0000x reference)
//
#include <hip/hip_runtime.h>

// Problem constants
constexpr int B_ = 32, C_ = 256, L_ = 1024, NE = 1024;
constexpr int NPTS = B_ * L_;            // 32768 points
// d_out flat float32 layout (reference return order)
constexpr long long LOSS_OFF = 0;
constexpr long long ZQ_OFF   = 1;                         // 8,388,608 elems
constexpr long long PERP_OFF = 1 + 8388608;               // 8388609
constexpr long long OH_OFF   = PERP_OFF + 1;              // 8388610
constexpr long long IDX_OFF  = OH_OFF + 33554432LL;       // 41943042
// workspace byte offsets (R2-R4 proved ws >= 272 KB at these offsets)
constexpr size_t WS_IDX = 0;            // int[32768]
constexpr size_t WS_CNT = 131072;       // uint[1024]
constexpr size_t WS_LP  = 135168;       // float[512]
constexpr size_t WS_E2  = 139264;       // float[1024]
constexpr size_t WS_Z2  = 143360;       // float[32768]

constexpr float MARGIN = 7e-4f;         // >= 2*(fp16 dot err) + d-quantization slack

typedef _Float16 f16x8 __attribute__((ext_vector_type(8)));
typedef float    f32x4 __attribute__((ext_vector_type(4)));

__device__ inline unsigned fkey(float f) {
  unsigned u = __float_as_uint(f);
  return (u & 0x80000000u) ? ~u : (u | 0x80000000u);
}
__device__ inline float unfkey(unsigned k) {
  unsigned u = (k & 0x80000000u) ? (k ^ 0x80000000u) : ~k;
  return __uint_as_float(u);
}

// ---- prep A: codebook fp32 -> fp16 fragments, pre-swizzled MFMA-order ----
__global__ __launch_bounds__(256) void k_prep_ehl(const float* __restrict__ emb,
                                                  uint4* __restrict__ ehlF) {
  const int u = blockIdx.x * 256 + threadIdx.x;   // 32768 units
  const int c16 = u & 15;
  const int s8  = (u >> 4) & 31;
  const int g   = u >> 9;
  const int code = g * 16 + c16;
  const float4* e4 = reinterpret_cast<const float4*>(emb + (size_t)code * C_) + s8 * 2;
  float4 v0 = e4[0], v1 = e4[1];
  const float f[8] = {v0.x, v0.y, v0.z, v0.w, v1.x, v1.y, v1.z, v1.w};
  unsigned w[4];
#pragma unroll
  for (int i = 0; i < 4; ++i) {
    _Float16 h0 = (_Float16)f[2 * i];
    _Float16 h1 = (_Float16)f[2 * i + 1];
    w[i] = (unsigned)__builtin_bit_cast(unsigned short, h0) |
           ((unsigned)__builtin_bit_cast(unsigned short, h1) << 16);
  }
  ehlF[u] = make_uint4(w[0], w[1], w[2], w[3]);
}

// ---- prep B: e2 (fp64 chain) + zero counts ----
__global__ __launch_bounds__(64) void k_prep_e2(const float* __restrict__ emb,
                                                float* __restrict__ e2,
                                                unsigned* __restrict__ counts) {
  const int j = blockIdx.x;
  const int t = threadIdx.x;
  const float* row = emb + (size_t)j * C_;
  double s = 0.0;
#pragma unroll
  for (int q = 0; q < 4; ++q) {
    float v = row[t + 64 * q];
    s += (double)v * (double)v;
  }
#pragma unroll
  for (int off = 32; off > 0; off >>= 1) s += __shfl_down(s, off);
  if (t == 0) { e2[j] = (float)s; counts[j] = 0u; }
}

// ---- z2[n] = sum_k z[b][k][l]^2, fp64, coalesced (R2-verified pattern) ----
// Also pre-warms z into L2/L3 for the screen's A-stage + rerank reads.
__global__ __launch_bounds__(256) void k_z2(const float* __restrict__ z,
                                            float* __restrict__ z2) {
  __shared__ double rd[256];
  const int tid = threadIdx.x, bid = blockIdx.x;
  const int b = bid >> 4, l0 = (bid & 15) << 6;
  const int li = tid & 63, kk = tid >> 6;
  const int l = l0 + li;
  const float* zp = z + (size_t)b * C_ * L_ + l;
  double s = 0.0;
#pragma unroll 8
  for (int k = kk * 64; k < kk * 64 + 64; ++k) {
    float v = zp[(size_t)k * L_];
    s += (double)v * (double)v;
  }
  rd[tid] = s;
  __syncthreads();
  if (kk == 0) {
    double t0 = rd[li] + rd[64 + li] + rd[128 + li] + rd[192 + li];
    z2[b * L_ + l] = (float)t0;
  }
}

// ---- fused MFMA screen + exact re-rank: 128 pts x 1024 codes per block ----
// LDS 78 KB -> 2 blocks/CU (4 waves/SIMD) for latency hiding. Screen MFMA
// operands bit-identical to verified R6-R8; rerank replays the bit-identical
// sequential-k fp32 fmaf chain; winner via packed-key LDS atomicMin.
__global__ __launch_bounds__(512, 2) void k_screen_rr(const float* __restrict__ z,
                                                      const float* __restrict__ emb,
                                                      const uint4* __restrict__ ehlF,
                                                      const float* __restrict__ e2g,
                                                      const float* __restrict__ z2g,
                                                      int* __restrict__ idxw,
                                                      unsigned* __restrict__ counts,
                                                      float* __restrict__ idx_out) {
  __shared__ _Float16 Az[128 * 256];          // 64 KB
  __shared__ unsigned short cand[128 * 32];   // 8 KB
  __shared__ unsigned long long bestkey[128]; // 1 KB
  __shared__ unsigned minkey[128];
  __shared__ unsigned ccnt[128];
  __shared__ float z2s[128];
  __shared__ int ids[128];
  __shared__ unsigned char dcnt[128];
  __shared__ float zcol[256];
  __shared__ int nbad;

  const int tid  = threadIdx.x;
  const int lane = tid & 63;
  const int wid  = tid >> 6;
  const int wr   = wid >> 2;          // 0..1 point half
  const int wc   = wid & 3;           // 0..3 code quarter (of chunk)
  const int l15  = lane & 15;
  const int lhi  = lane >> 4;         // 0..3
  const int n0   = blockIdx.x * 128;
  const int b    = blockIdx.x >> 3;
  const int l0   = (blockIdx.x & 7) << 7;

  // A transpose+convert: z fp32 -> Az[p][k] f16, XOR slot swizzle
  {
    const float4* z4 = reinterpret_cast<const float4*>(z + (size_t)b * (C_ * L_) + l0);
    const int l4 = tid & 31;
    const int kp = tid >> 5;            // 0..15
#pragma unroll
    for (int rr = 0; rr < 8; ++rr) {
      const int k0 = rr * 32 + kp * 2;
      float4 a0 = z4[(size_t)k0 * (L_ / 4) + l4];
      float4 a1 = z4[(size_t)(k0 + 1) * (L_ / 4) + l4];
      const float av0[4] = {a0.x, a0.y, a0.z, a0.w};
      const float av1[4] = {a1.x, a1.y, a1.z, a1.w};
#pragma unroll
      for (int j = 0; j < 4; ++j) {
        _Float16 h0 = (_Float16)av0[j];
        _Float16 h1 = (_Float16)av1[j];
        unsigned pk = (unsigned)__builtin_bit_cast(unsigned short, h0) |
                      ((unsigned)__builtin_bit_cast(unsigned short, h1) << 16);
        const int p = l4 * 4 + j;
        const int slot = k0 >> 3;
        const int addr = p * 256 + ((slot ^ (p & 31)) << 3) + (k0 & 7);
        *reinterpret_cast<unsigned*>(&Az[addr]) = pk;
      }
    }
  }
  if (tid < 128) { minkey[tid] = 0xFFFFFFFFu; ccnt[tid] = 0u; }
  if (tid == 0) nbad = 0;
  __syncthreads();

  f32x4 acc[4][4];
#pragma unroll
  for (int i = 0; i < 4; ++i)
#pragma unroll
    for (int j = 0; j < 4; ++j) acc[i][j] = (f32x4){0.f, 0.f, 0.f, 0.f};

  for (int ph = 0; ph < 8; ++ph) {
    const int cc = ph >> 1;
    const int kh = ph & 1;
#pragma unroll
    for (int s = 0; s < 4; ++s) {
      const int slotA = kh * 16 + s * 4 + lhi;
      f16x8 bfr[4];
#pragma unroll
      for (int tj = 0; tj < 4; ++tj) {
        const int g = cc * 16 + wc * 4 + tj;
        bfr[tj] = __builtin_bit_cast(f16x8, ehlF[(g * 32 + slotA) * 16 + l15]);
      }
      f16x8 afr[4];
#pragma unroll
      for (int ti = 0; ti < 4; ++ti) {
        const int pA = wr * 64 + ti * 16 + l15;
        const int swzA = slotA ^ (((ti & 1) << 4) ^ l15);
        afr[ti] = *reinterpret_cast<const f16x8*>(&Az[pA * 256 + swzA * 8]);
      }
#pragma unroll
      for (int ti = 0; ti < 4; ++ti)
#pragma unroll
        for (int tj = 0; tj < 4; ++tj)
          acc[ti][tj] = __builtin_amdgcn_mfma_f32_16x16x32_f16(
              afr[ti], bfr[tj], acc[ti][tj], 0, 0, 0);
    }
    if (kh == 1) {
      float e2r[4];
#pragma unroll
      for (int tj = 0; tj < 4; ++tj)
        e2r[tj] = e2g[cc * 256 + wc * 64 + tj * 16 + l15];
#pragma unroll
      for (int ti = 0; ti < 4; ++ti) {
#pragma unroll
        for (int r = 0; r < 4; ++r) {
          float m = e2r[0] - 2.0f * acc[ti][0][r];
#pragma unroll
          for (int tj = 1; tj < 4; ++tj) {
            float v = e2r[tj] - 2.0f * acc[ti][tj][r];
            m = fminf(m, v);
          }
          m = fminf(m, __shfl_xor(m, 1));
          m = fminf(m, __shfl_xor(m, 2));
          m = fminf(m, __shfl_xor(m, 4));
          m = fminf(m, __shfl_xor(m, 8));
          if (l15 == 0) {
            const int p = wr * 64 + ti * 16 + lhi * 4 + r;
            atomicMin(&minkey[p], fkey(m));
          }
        }
      }
      __syncthreads();   // chunk mins visible; later chunks only shrink thr
#pragma unroll
      for (int ti = 0; ti < 4; ++ti) {
#pragma unroll
        for (int r = 0; r < 4; ++r) {
          const int p = wr * 64 + ti * 16 + lhi * 4 + r;
          const float thr = unfkey(minkey[p]) + MARGIN;
#pragma unroll
          for (int tj = 0; tj < 4; ++tj) {
            float s = e2r[tj] - 2.0f * acc[ti][tj][r];
            if (s <= thr) {
              unsigned pos = atomicAdd(&ccnt[p], 1u);
              if (pos < 32u)
                cand[p * 32 + pos] = (unsigned short)(cc * 256 + wc * 64 + tj * 16 + l15);
            }
          }
        }
      }
#pragma unroll
      for (int i = 0; i < 4; ++i)
#pragma unroll
        for (int j = 0; j < 4; ++j) acc[i][j] = (f32x4){0.f, 0.f, 0.f, 0.f};
    }
  }
  __syncthreads();

  // ---- re-rank phase (in-block) ----
  if (tid < 128) {
    z2s[tid] = z2g[n0 + tid];
    bestkey[tid] = ~0ULL;
    const unsigned cnt = ccnt[tid];
    if (cnt == 1u) {
      dcnt[tid] = 0;
      ids[tid] = cand[tid * 32];
    } else if (cnt <= 32u) {           // 2..32
      dcnt[tid] = (unsigned char)cnt;
    } else {                           // overflow -> block full scan
      dcnt[tid] = 0xFF;
      atomicAdd(&nbad, 1);
    }
  }
  __syncthreads();

  // exact pair dots: 4 threads/point; sequential-k fmaf chain (bit-exact)
  {
    const int p = tid >> 2, j = tid & 3;
    const int cnt = (dcnt[p] == 0xFF) ? 0 : (int)dcnt[p];
    const float* zc = z + (size_t)b * (C_ * L_) + l0 + p;
    for (int q = j; q < cnt; q += 4) {
      const int c = cand[p * 32 + q];
      const float4* er = reinterpret_cast<const float4*>(emb + (size_t)c * C_);
      float acc2 = 0.f;
#pragma unroll 4
      for (int k4 = 0; k4 < 64; ++k4) {
        float4 e = er[k4];
        acc2 = fmaf(zc[(size_t)(k4 * 4 + 0) * L_], e.x, acc2);
        acc2 = fmaf(zc[(size_t)(k4 * 4 + 1) * L_], e.y, acc2);
        acc2 = fmaf(zc[(size_t)(k4 * 4 + 2) * L_], e.z, acc2);
        acc2 = fmaf(zc[(size_t)(k4 * 4 + 3) * L_], e.w, acc2);
      }
      const float d = (z2s[p] + e2g[c]) - 2.0f * acc2;   // numpy op order
      const unsigned long long key =
          ((unsigned long long)fkey(d) << 32) | (unsigned)c;
      atomicMin(&bestkey[p], key);
    }
  }
  __syncthreads();

  // rare overflow fallback: full 1024-code scan, block-cooperative
  if (nbad > 0) {
    for (int p = 0; p < 128; ++p) {
      if (dcnt[p] != 0xFF) continue;
      const float* zc = z + (size_t)b * (C_ * L_) + l0 + p;
      if (tid < 256) zcol[tid] = zc[(size_t)tid * L_];
      __syncthreads();
#pragma unroll
      for (int h = 0; h < 2; ++h) {
        const int c = tid * 2 + h;
        const float* er = emb + (size_t)c * C_;
        float acc2 = 0.f;
        for (int k = 0; k < 256; ++k) acc2 = fmaf(zcol[k], er[k], acc2);
        const float d = (z2s[p] + e2g[c]) - 2.0f * acc2;
        const unsigned long long key =
            ((unsigned long long)fkey(d) << 32) | (unsigned)c;
        atomicMin(&bestkey[p], key);
      }
      __syncthreads();
    }
  }

  // finalize winners
  if (tid < 128) {
    const int n = n0 + tid;
    int id = ids[tid];
    if (dcnt[tid] != 0) id = (int)(unsigned)(bestkey[tid] & 0xFFFFFFFFu);
    idxw[n] = id;
    idx_out[n] = (float)id;
    atomicAdd(&counts[id], 1u);
  }
}

// ---- gather (z_q straight-through) + masked loss partials ----
__global__ __launch_bounds__(256) void k_zq_loss(const float* __restrict__ z,
                                                 const float* __restrict__ emb,
                                                 const float* __restrict__ mask,
                                                 const int* __restrict__ idxw,
                                                 float* __restrict__ zq_out,
                                                 float* __restrict__ lp) {
  __shared__ float eq[256][66];
  __shared__ float red[256];
  const int tid = threadIdx.x, bid = blockIdx.x;
  const int b = bid >> 4, l0 = (bid & 15) << 6, n0 = bid << 6;
  {
    const int r  = tid >> 2;
    const int kq = tid & 3;
    const int id = idxw[n0 + r];
    const float4* e4 = reinterpret_cast<const float4*>(emb + (size_t)id * C_);
#pragma unroll
    for (int rep = 0; rep < 16; ++rep) {
      int c4 = rep * 4 + kq;
      float4 v = e4[c4];
      eq[c4 * 4 + 0][r] = v.x;
      eq[c4 * 4 + 1][r] = v.y;
      eq[c4 * 4 + 2][r] = v.z;
      eq[c4 * 4 + 3][r] = v.w;
    }
  }
  __syncthreads();
  const int lq = tid & 63, cg = tid >> 6;
  const float m = mask[b * L_ + l0 + lq];
  const size_t zbase = (size_t)b * C_ * L_ + l0 + lq;
  float s = 0.f;
#pragma unroll 4
  for (int ci = 0; ci < 64; ++ci) {
    int c = cg * 64 + ci;
    float zv = z[zbase + (size_t)c * L_];
    float q  = eq[c][lq];
    float diff = q - zv;                         // fl(z_q - zp)
    zq_out[zbase + (size_t)c * L_] = zv + diff;  // straight-through
    float t = diff * m;
    s = fmaf(t, t, s);
  }
  red[tid] = s;
  __syncthreads();
  for (int off = 128; off > 0; off >>= 1) {
    if (tid < off) red[tid] += red[tid + off];
    __syncthreads();
  }
  if (tid == 0) lp[bid] = red[0];
}

// ---- one_hot: single pass, values on the fly (base only 8B-aligned) ----
__global__ __launch_bounds__(256) void k_onehot(const int* __restrict__ idxw,
                                                float* __restrict__ oh) {
  const int tid = threadIdx.x, bid = blockIdx.x;
#pragma unroll
  for (int r = 0; r < 16; ++r) {
    const int n = bid * 16 + r;
    const int id = idxw[n];
    float* row = oh + (size_t)n * NE;
    const int c = tid * 4;
    float2 v0, v1;
    v0.x = (c + 0 == id) ? 1.f : 0.f;
    v0.y = (c + 1 == id) ? 1.f : 0.f;
    v1.x = (c + 2 == id) ? 1.f : 0.f;
    v1.y = (c + 3 == id) ? 1.f : 0.f;
    *reinterpret_cast<float2*>(row + c)     = v0;
    *reinterpret_cast<float2*>(row + c + 2) = v1;
  }
}

// ---- deterministic loss total + perplexity (lp: 512 entries) ----
__global__ __launch_bounds__(256) void k_final(const float* __restrict__ lp,
                                               const unsigned int* __restrict__ counts,
                                               float* __restrict__ out) {
  __shared__ float red[256];
  const int t = threadIdx.x;
  red[t] = lp[t] + lp[t + 256];
  __syncthreads();
  for (int off = 128; off > 0; off >>= 1) {
    if (t < off) red[t] += red[t + off];
    __syncthreads();
  }
  if (t == 0) {
    float m = red[0] / 8388608.0f;
    out[LOSS_OFF] = m + 0.25f * m;
  }
  __syncthreads();
  float h = 0.f;
#pragma unroll
  for (int q = 0; q < 4; ++q) {
    int jj = t * 4 + q;
    float em = (float)counts[jj] * (1.0f / 32768.0f);
    h += em * logf(em + 1e-10f);
  }
  red[t] = h;
  __syncthreads();
  for (int off = 128; off > 0; off >>= 1) {
    if (t < off) red[t] += red[t + off];
    __syncthreads();
  }
  if (t == 0) out[PERP_OFF] = expf(-red[0]);
}

extern "C" void kernel_launch(void* const* d_in, const int* in_sizes, int n_in,
                              void* d_out, int out_size, void* d_ws, size_t ws_size,
                              hipStream_t stream) {
  const float* z    = (const float*)d_in[0];
  const float* mask = (const float*)d_in[1];
  const float* emb  = (const float*)d_in[2];
  float* out = (float*)d_out;
  char* ws = (char*)d_ws;
  int* idxw            = (int*)(ws + WS_IDX);
  unsigned int* counts = (unsigned int*)(ws + WS_CNT);
  float* lp            = (float*)(ws + WS_LP);
  float* e2            = (float*)(ws + WS_E2);
  float* z2            = (float*)(ws + WS_Z2);

  // ehlF scratch lives in the one_hot output region; k_onehot (the only
  // writer of that region) runs strictly after k_screen_rr on the stream.
  uintptr_t sp = (uintptr_t)(out + OH_OFF);
  sp = (sp + 15) & ~(uintptr_t)15;
  uint4* ehlF = (uint4*)sp;                                 // 512 KB

  hipLaunchKernelGGL(k_prep_ehl, dim3(128), dim3(256), 0, stream, emb, ehlF);
  hipLaunchKernelGGL(k_prep_e2, dim3(NE), dim3(64), 0, stream, emb, e2, counts);
  hipLaunchKernelGGL(k_z2, dim3(512), dim3(256), 0, stream, z, z2);
  hipLaunchKernelGGL(k_screen_rr, dim3(256), dim3(512), 0, stream,
                     z, emb, ehlF, e2, z2, idxw, counts, out + IDX_OFF);
  hipLaunchKernelGGL(k_zq_loss, dim3(512), dim3(256), 0, stream,
                     z, emb, mask, idxw, out + ZQ_OFF, lp);
  hipLaunchKernelGGL(k_onehot, dim3(NPTS / 16), dim3(256), 0, stream,
                     idxw, out + OH_OFF);
  hipLaunchKernelGGL(k_final, dim3(1), dim3(256), 0, stream, lp, counts, out);
}